// Round 1
// baseline (352.038 us; speedup 1.0000x reference)
//
#include <hip/hip_runtime.h>
#include <math.h>

#define D_DIM 256
#define K_EMB 1024
#define HW_SZ 1024
#define N_TOT 32768
#define BN 64
#define BK 64
#define BD 64
#define ES_LD (BD + 4)   // pad -> 2-way-max bank aliasing on es reads (free per m136)

// ---------------------------------------------------------------- enorm ----
__global__ __launch_bounds__(256) void vq_enorm(const float* __restrict__ E,
                                                float* __restrict__ enorm) {
  int tid = blockIdx.x * 256 + threadIdx.x;  // 0..4095, 4 threads per k
  int k = tid >> 2;
  int part = tid & 3;
  const float* p = E + k * D_DIM + part * 64;
  float s = 0.f;
#pragma unroll
  for (int i = 0; i < 16; ++i) {
    float4 v = *(const float4*)(p + i * 4);
    s = fmaf(v.x, v.x, s); s = fmaf(v.y, v.y, s);
    s = fmaf(v.z, v.z, s); s = fmaf(v.w, v.w, s);
  }
  s += __shfl_xor(s, 1, 4);
  s += __shfl_xor(s, 2, 4);
  if (part == 0) enorm[k] = s;
}

// ----------------------------------------------------------------- main ----
__global__ __launch_bounds__(256) void vq_main(const float* __restrict__ X,
                                               const float* __restrict__ E,
                                               const float* __restrict__ enorm,
                                               float* __restrict__ out,
                                               float* __restrict__ counts,
                                               float* __restrict__ lossacc) {
  __shared__ float xs[BD][BN];          // [d][n] tile, 16 KB
  __shared__ float es[BK][ES_LD];       // [k][d] tile, 17 KB
  __shared__ float red_val[16][BN];     // per-kc partial argmin
  __shared__ int   red_idx[16][BN];
  __shared__ float enorm_s[K_EMB];
  __shared__ float best_val[BN];
  __shared__ int   best_idx[BN];
  __shared__ float loss_part[4];

  const int t = threadIdx.x;
  const int n0 = blockIdx.x * BN;
  const int b = n0 >> 10;
  const int hw0 = n0 & 1023;
  const float* Xb = X + b * (D_DIM * HW_SZ);

  const int tn = t & 15;   // n-quad owner
  const int tk = t >> 4;   // k-quad owner

  // stage enorm once (4 floats/thread)
  *(float4*)&enorm_s[t * 4] = *(const float4*)&enorm[t * 4];
  if (t < BN) { best_val[t] = INFINITY; best_idx[t] = 0; }

  float acc[4][4];

  for (int kc = 0; kc < K_EMB / BK; ++kc) {
#pragma unroll
    for (int i = 0; i < 4; ++i)
#pragma unroll
      for (int j = 0; j < 4; ++j) acc[i][j] = 0.f;

    for (int dc = 0; dc < D_DIM / BD; ++dc) {
      const int d0 = dc * BD;
      __syncthreads();  // prior tile reads (and prior red reads) done
      {
        const int row = t >> 4;            // 0..15
        const int col = (t & 15) << 2;     // 0..60
#pragma unroll
        for (int it = 0; it < 4; ++it) {   // X tile: [dd][nn]
          const int dd = row + it * 16;
          float4 v = *(const float4*)(Xb + (d0 + dd) * HW_SZ + hw0 + col);
          *(float4*)&xs[dd][col] = v;
        }
        const float* Ebase = E + (kc * BK) * D_DIM + d0;
#pragma unroll
        for (int it = 0; it < 4; ++it) {   // E tile: [kk][dd] (no transpose)
          const int kk = row + it * 16;
          float4 v = *(const float4*)(Ebase + kk * D_DIM + col);
          *(float4*)&es[kk][col] = v;
        }
      }
      __syncthreads();

#pragma unroll 4
      for (int dd = 0; dd < BD; dd += 4) {
        float4 x0 = *(const float4*)&xs[dd + 0][tn << 2];
        float4 x1 = *(const float4*)&xs[dd + 1][tn << 2];
        float4 x2 = *(const float4*)&xs[dd + 2][tn << 2];
        float4 x3 = *(const float4*)&xs[dd + 3][tn << 2];
        float4 e0 = *(const float4*)&es[(tk << 2) + 0][dd];
        float4 e1 = *(const float4*)&es[(tk << 2) + 1][dd];
        float4 e2 = *(const float4*)&es[(tk << 2) + 2][dd];
        float4 e3 = *(const float4*)&es[(tk << 2) + 3][dd];
#define DOT_STEP(J, EV)                                     \
        acc[0][J] = fmaf(x0.x, EV.x, acc[0][J]);            \
        acc[0][J] = fmaf(x1.x, EV.y, acc[0][J]);            \
        acc[0][J] = fmaf(x2.x, EV.z, acc[0][J]);            \
        acc[0][J] = fmaf(x3.x, EV.w, acc[0][J]);            \
        acc[1][J] = fmaf(x0.y, EV.x, acc[1][J]);            \
        acc[1][J] = fmaf(x1.y, EV.y, acc[1][J]);            \
        acc[1][J] = fmaf(x2.y, EV.z, acc[1][J]);            \
        acc[1][J] = fmaf(x3.y, EV.w, acc[1][J]);            \
        acc[2][J] = fmaf(x0.z, EV.x, acc[2][J]);            \
        acc[2][J] = fmaf(x1.z, EV.y, acc[2][J]);            \
        acc[2][J] = fmaf(x2.z, EV.z, acc[2][J]);            \
        acc[2][J] = fmaf(x3.z, EV.w, acc[2][J]);            \
        acc[3][J] = fmaf(x0.w, EV.x, acc[3][J]);            \
        acc[3][J] = fmaf(x1.w, EV.y, acc[3][J]);            \
        acc[3][J] = fmaf(x2.w, EV.z, acc[3][J]);            \
        acc[3][J] = fmaf(x3.w, EV.w, acc[3][J]);
        DOT_STEP(0, e0)
        DOT_STEP(1, e1)
        DOT_STEP(2, e2)
        DOT_STEP(3, e3)
#undef DOT_STEP
      }
    }

    // per-thread reduce 4 k's for each of its 4 n's (ascending k: first-idx ties)
    {
      const int k0 = kc * BK + (tk << 2);
      const float en0 = enorm_s[k0 + 0];
      const float en1 = enorm_s[k0 + 1];
      const float en2 = enorm_s[k0 + 2];
      const float en3 = enorm_s[k0 + 3];
#pragma unroll
      for (int i = 0; i < 4; ++i) {
        float v = fmaf(-2.f, acc[i][0], en0); int bi = k0;
        float v1 = fmaf(-2.f, acc[i][1], en1); if (v1 < v) { v = v1; bi = k0 + 1; }
        float v2 = fmaf(-2.f, acc[i][2], en2); if (v2 < v) { v = v2; bi = k0 + 2; }
        float v3 = fmaf(-2.f, acc[i][3], en3); if (v3 < v) { v = v3; bi = k0 + 3; }
        red_val[tk][(tn << 2) + i] = v;
        red_idx[tk][(tn << 2) + i] = bi;
      }
    }
    __syncthreads();
    if (t < BN) {   // merge 16 partials, ascending tk => ascending k
      float bv = best_val[t]; int bidx = best_idx[t];
#pragma unroll
      for (int r = 0; r < 16; ++r) {
        float v = red_val[r][t];
        if (v < bv) { bv = v; bidx = red_idx[r][t]; }
      }
      best_val[t] = bv; best_idx[t] = bidx;
    }
    // next iteration's first __syncthreads separates red reads from re-writes
  }

  __syncthreads();  // best_idx final, visible to all

  if (t < BN) atomicAdd(&counts[best_idx[t]], 1.0f);

  // epilogue: write quantized (== quantized_st) + fused loss
  float lsum = 0.f;
  {
    const int nn = t & 63;
    const int drow = t >> 6;  // 0..3, whole wave shares drow
    const int kbest = best_idx[nn];
    const float* Ek = E + kbest * D_DIM;
    const float* Xn = Xb + hw0 + nn;
    float* On = out + b * (D_DIM * HW_SZ) + hw0 + nn;
#pragma unroll 8
    for (int d = drow; d < D_DIM; d += 4) {
      float q = Ek[d];          // L2-resident gather
      float x = Xn[d * HW_SZ];  // coalesced across lanes
      On[d * HW_SZ] = q;        // coalesced across lanes
      float diff = q - x;
      lsum = fmaf(diff, diff, lsum);
    }
  }
#pragma unroll
  for (int off = 32; off >= 1; off >>= 1) lsum += __shfl_xor(lsum, off);
  if ((t & 63) == 0) loss_part[t >> 6] = lsum;
  __syncthreads();
  if (t == 0)
    atomicAdd(lossacc, loss_part[0] + loss_part[1] + loss_part[2] + loss_part[3]);
}

// ------------------------------------------------------------- finalize ----
__global__ __launch_bounds__(256) void vq_finalize(const float* __restrict__ counts,
                                                   const float* __restrict__ lossacc,
                                                   float* __restrict__ out_tail) {
  __shared__ float part[4];
  const int t = threadIdx.x;
  float s = 0.f;
#pragma unroll
  for (int k = t; k < K_EMB; k += 256) {
    float p = counts[k] * (1.0f / 32768.0f);
    s = fmaf(p, logf(p + 1e-10f), s);  // p==0 -> 0*log(1e-10)==0, matches ref
  }
#pragma unroll
  for (int off = 32; off >= 1; off >>= 1) s += __shfl_xor(s, off);
  if ((t & 63) == 0) part[t >> 6] = s;
  __syncthreads();
  if (t == 0) {
    float tot = part[0] + part[1] + part[2] + part[3];
    out_tail[0] = 1.25f * lossacc[0] * (1.0f / 8388608.0f);  // (1+0.25)*MSE
    out_tail[1] = expf(-tot);
  }
}

// ---------------------------------------------------------------- launch ---
extern "C" void kernel_launch(void* const* d_in, const int* in_sizes, int n_in,
                              void* d_out, int out_size, void* d_ws, size_t ws_size,
                              hipStream_t stream) {
  const float* X = (const float*)d_in[0];   // [32,256,32,32]
  const float* E = (const float*)d_in[1];   // [1024,256]
  float* out = (float*)d_out;               // 8388608 + 1 + 1
  float* ws = (float*)d_ws;
  float* enorm = ws;          // [1024]
  float* counts = ws + 1024;  // [1024]
  float* lossa = ws + 2048;   // [1]

  hipMemsetAsync(d_ws, 0, 2049 * sizeof(float), stream);
  vq_enorm<<<16, 256, 0, stream>>>(E, enorm);
  vq_main<<<N_TOT / BN, 256, 0, stream>>>(X, E, enorm, out, counts, lossa);
  vq_finalize<<<1, 256, 0, stream>>>(counts, lossa, out + 8388608);
}

// Round 2
// 179.896 us; speedup vs baseline: 1.9569x; 1.9569x over previous
//
#include <hip/hip_runtime.h>
#include <math.h>

typedef __attribute__((ext_vector_type(8))) short short8;
typedef __attribute__((ext_vector_type(4))) float float4v;

#define D_DIM 256
#define K_EMB 1024
#define HW_SZ 1024
#define N_TOT 32768
#define SMP_B (D_DIM * HW_SZ)  // per-batch stride in X (floats)

// ---- bf16 hi/lo split helpers (RNE) ----
__device__ __forceinline__ unsigned short f2bf(float x) {
  unsigned int u = __builtin_bit_cast(unsigned int, x);
  return (unsigned short)((u + 0x7fffu + ((u >> 16) & 1u)) >> 16);
}
__device__ __forceinline__ float bf2f(unsigned short h) {
  unsigned int u = ((unsigned int)h) << 16;
  return __builtin_bit_cast(float, u);
}

// ---- async global->LDS, 16B/lane (dest = wave-uniform base + lane*16) ----
typedef const __attribute__((address_space(1))) void GV;
typedef __attribute__((address_space(3))) void LV;
__device__ __forceinline__ void async16(const void* g, void* l) {
  __builtin_amdgcn_global_load_lds((GV*)g, (LV*)l, 16, 0, 0);
}

// ------------------------------------------------------------------ prep ----
// Ehi/Elo: [1024][256] bf16 (d-contig, K-major for MFMA A-frags); enorm fp32 exact.
__global__ __launch_bounds__(256) void vq_prep(const float* __restrict__ E,
                                               unsigned short* __restrict__ Ehi,
                                               unsigned short* __restrict__ Elo,
                                               float* __restrict__ enorm) {
  int tid = blockIdx.x * 256 + threadIdx.x;  // 32768 threads, 32 per code
  int c = tid >> 5;
  int d0 = (tid & 31) * 8;
  const float* p = E + c * D_DIM + d0;
  float s = 0.f;
  short8 hv, lv;
#pragma unroll
  for (int j = 0; j < 8; ++j) {
    float x = p[j];
    s = fmaf(x, x, s);
    unsigned short h = f2bf(x);
    hv[j] = (short)h;
    lv[j] = (short)f2bf(x - bf2f(h));
  }
  *(short8*)(Ehi + c * D_DIM + d0) = hv;
  *(short8*)(Elo + c * D_DIM + d0) = lv;
#pragma unroll
  for (int off = 1; off <= 16; off <<= 1) s += __shfl_xor(s, off);
  if ((tid & 31) == 0) enorm[c] = s;
}

// ------------------------------------------------------------------ gemm ----
// Per block: 128 codes (M) x 128 samples (N), contraction D=256 in BK=32 chunks.
// S = x.e via 3-term bf16 split; distances d = enorm - 2S; per-sample argmin
// over the block's 128-code stripe -> partials [8 stripes][32768].
__global__ __launch_bounds__(256, 2) void vq_gemm(
    const float* __restrict__ X, const unsigned short* __restrict__ Ehi,
    const unsigned short* __restrict__ Elo, const float* __restrict__ enorm,
    float* __restrict__ pval, int* __restrict__ pidx) {
  __shared__ unsigned short es_hi[128 * 32];  // 8 KB [code][d] d-contig
  __shared__ unsigned short es_lo[128 * 32];  // 8 KB
  __shared__ float xs[32 * 128];              // 16 KB [d][smp] smp-contig (X native)
  __shared__ float rv[2][128];
  __shared__ int ri[2][128];

  const int t = threadIdx.x;
  const int i = blockIdx.x;
  // XCD-aware swizzle: all 8 code-stripes of one sample-block share i&7 -> same XCD
  const int cblk = (i >> 3) & 7;                 // code stripe 0..7
  const int sblk = ((i >> 6) << 3) | (i & 7);    // sample block 0..255

  const int b = sblk >> 3;
  const int hw0 = (sblk & 7) * 128;

  const int lane = t & 63;
  const int wv = t >> 6;
  const int wm = wv >> 1;   // code half (0:codes 0..63, 1:64..127)
  const int wn = wv & 1;    // sample half
  const int l15 = lane & 15;
  const int q = lane >> 4;

  float4v acc[4][4];
#pragma unroll
  for (int a = 0; a < 4; ++a)
#pragma unroll
    for (int c = 0; c < 4; ++c) acc[a][c] = {0.f, 0.f, 0.f, 0.f};

  const int xrow = t >> 5, xseg = t & 31;
  const int erow = t >> 2, eseg = t & 3;
  const float* xbase = X + b * SMP_B + hw0 + xseg * 4;
  const unsigned short* ehb = Ehi + (cblk * 128 + erow) * D_DIM + eseg * 8;
  const unsigned short* elb = Elo + (cblk * 128 + erow) * D_DIM + eseg * 8;
  char* xs_b = (char*)xs;
  char* eh_b = (char*)es_hi;
  char* el_b = (char*)es_lo;

  for (int dc = 0; dc < 8; ++dc) {
    const int d0 = dc * 32;
    // stage X tile (fp32, 16 KB) + E hi/lo tiles (8 KB each) async
#pragma unroll
    for (int p = 0; p < 4; ++p)
      async16(xbase + (d0 + xrow + p * 8) * HW_SZ, xs_b + t * 16 + p * 4096);
#pragma unroll
    for (int p = 0; p < 2; ++p) {
      async16(ehb + p * 64 * D_DIM + d0, eh_b + t * 16 + p * 4096);
      async16(elb + p * 64 * D_DIM + d0, el_b + t * 16 + p * 4096);
    }
    __syncthreads();  // barrier drains vmcnt -> tiles visible

    // E fragments: A[m=l15][k=q*8+j], one ds_read_b128 each
    short8 ah[4], al[4];
#pragma unroll
    for (int mi = 0; mi < 4; ++mi) {
      int row = wm * 64 + mi * 16 + l15;
      ah[mi] = *(const short8*)&es_hi[row * 32 + q * 8];
      al[mi] = *(const short8*)&es_lo[row * 32 + q * 8];
    }
    // X fragments: B[k=q*8+j][n=l15], strided fp32 reads + in-reg hi/lo convert
    short8 xh[4], xl[4];
#pragma unroll
    for (int ni = 0; ni < 4; ++ni) {
      int ncol = wn * 64 + ni * 16 + l15;
      const float* colp = &xs[q * 8 * 128 + ncol];
      short8 hv, lv;
#pragma unroll
      for (int j = 0; j < 8; ++j) {
        float x = colp[j * 128];
        unsigned short h = f2bf(x);
        hv[j] = (short)h;
        lv[j] = (short)f2bf(x - bf2f(h));
      }
      xh[ni] = hv;
      xl[ni] = lv;
    }
    // 3-term split MFMA; 16 independent accs between same-acc reuse
#pragma unroll
    for (int mi = 0; mi < 4; ++mi)
#pragma unroll
      for (int ni = 0; ni < 4; ++ni)
        acc[mi][ni] = __builtin_amdgcn_mfma_f32_16x16x32_bf16(ah[mi], xh[ni], acc[mi][ni], 0, 0, 0);
#pragma unroll
    for (int mi = 0; mi < 4; ++mi)
#pragma unroll
      for (int ni = 0; ni < 4; ++ni)
        acc[mi][ni] = __builtin_amdgcn_mfma_f32_16x16x32_bf16(ah[mi], xl[ni], acc[mi][ni], 0, 0, 0);
#pragma unroll
    for (int mi = 0; mi < 4; ++mi)
#pragma unroll
      for (int ni = 0; ni < 4; ++ni)
        acc[mi][ni] = __builtin_amdgcn_mfma_f32_16x16x32_bf16(al[mi], xh[ni], acc[mi][ni], 0, 0, 0);
    __syncthreads();  // all frag reads done before next stage overwrites
  }

  // ---- per-sample argmin over this block's 128 codes ----
  // C/D layout: col(lane&15)=sample, row(q*4+reg)=code
  float en[16];
#pragma unroll
  for (int mi = 0; mi < 4; ++mi)
#pragma unroll
    for (int r = 0; r < 4; ++r)
      en[mi * 4 + r] = enorm[cblk * 128 + wm * 64 + mi * 16 + q * 4 + r];

#pragma unroll
  for (int ni = 0; ni < 4; ++ni) {
    float bv = 1e30f;
    int bc = 0;
#pragma unroll
    for (int mi = 0; mi < 4; ++mi)
#pragma unroll
      for (int r = 0; r < 4; ++r) {
        float v = fmaf(-2.f, acc[mi][ni][r], en[mi * 4 + r]);
        if (v < bv) { bv = v; bc = wm * 64 + mi * 16 + q * 4 + r; }  // ascending c
      }
#pragma unroll
    for (int off = 16; off <= 32; off <<= 1) {  // merge the 4 q-groups
      float ov = __shfl_xor(bv, off);
      int oc = __shfl_xor(bc, off);
      if (ov < bv || (ov == bv && oc < bc)) { bv = ov; bc = oc; }
    }
    if (q == 0) {
      rv[wm][wn * 64 + ni * 16 + l15] = bv;
      ri[wm][wn * 64 + ni * 16 + l15] = cblk * 128 + bc;
    }
  }
  __syncthreads();
  if (t < 128) {  // merge code halves (wm0 codes < wm1 codes: tie keeps wm0)
    float v0 = rv[0][t];
    int c0 = ri[0][t];
    float v1 = rv[1][t];
    int c1 = ri[1][t];
    if (v1 < v0) { v0 = v1; c0 = c1; }
    pval[cblk * N_TOT + sblk * 128 + t] = v0;
    pidx[cblk * N_TOT + sblk * 128 + t] = c0;
  }
}

// -------------------------------------------------------------- epilogue ----
__global__ __launch_bounds__(256) void vq_epi(
    const float* __restrict__ X, const float* __restrict__ E,
    const float* __restrict__ pval, const int* __restrict__ pidx,
    float* __restrict__ out, float* __restrict__ counts,
    float* __restrict__ lossacc) {
  __shared__ int best_idx[64];
  __shared__ float loss_part[4];
  const int t = threadIdx.x;
  const int n0 = blockIdx.x * 64;
  const int b = n0 >> 10;
  const int hw0 = n0 & 1023;

  if (t < 64) {
    int n = n0 + t;
    float bv = 1e30f;
    int bc = 0;
#pragma unroll
    for (int s = 0; s < 8; ++s) {  // ascending stripe = ascending code range
      float v = pval[s * N_TOT + n];
      int c = pidx[s * N_TOT + n];
      if (v < bv || (v == bv && c < bc)) { bv = v; bc = c; }
    }
    best_idx[t] = bc;
    atomicAdd(&counts[bc], 1.0f);
  }
  __syncthreads();

  float lsum = 0.f;
  {
    const int nn = t & 63;
    const int drow = t >> 6;
    const int kbest = best_idx[nn];
    const float* Ek = E + kbest * D_DIM;
    const float* Xn = X + b * SMP_B + hw0 + nn;
    float* On = out + b * SMP_B + hw0 + nn;
#pragma unroll 8
    for (int d = drow; d < D_DIM; d += 4) {
      float qv = Ek[d];          // L2/L3-hot gather
      float xv = Xn[d * HW_SZ];  // coalesced across lanes
      On[d * HW_SZ] = qv;        // coalesced across lanes
      float diff = qv - xv;
      lsum = fmaf(diff, diff, lsum);
    }
  }
#pragma unroll
  for (int off = 32; off >= 1; off >>= 1) lsum += __shfl_xor(lsum, off);
  if ((t & 63) == 0) loss_part[t >> 6] = lsum;
  __syncthreads();
  if (t == 0)
    atomicAdd(lossacc, loss_part[0] + loss_part[1] + loss_part[2] + loss_part[3]);
}

// -------------------------------------------------------------- finalize ----
__global__ __launch_bounds__(256) void vq_finalize(const float* __restrict__ counts,
                                                   const float* __restrict__ lossacc,
                                                   float* __restrict__ out_tail) {
  __shared__ float part[4];
  const int t = threadIdx.x;
  float s = 0.f;
#pragma unroll
  for (int k = t; k < K_EMB; k += 256) {
    float p = counts[k] * (1.0f / 32768.0f);
    s = fmaf(p, logf(p + 1e-10f), s);
  }
#pragma unroll
  for (int off = 32; off >= 1; off >>= 1) s += __shfl_xor(s, off);
  if ((t & 63) == 0) part[t >> 6] = s;
  __syncthreads();
  if (t == 0) {
    float tot = part[0] + part[1] + part[2] + part[3];
    out_tail[0] = 1.25f * lossacc[0] * (1.0f / 8388608.0f);
    out_tail[1] = expf(-tot);
  }
}

// ---------------------------------------------------------------- launch ----
extern "C" void kernel_launch(void* const* d_in, const int* in_sizes, int n_in,
                              void* d_out, int out_size, void* d_ws, size_t ws_size,
                              hipStream_t stream) {
  const float* X = (const float*)d_in[0];  // [32,256,32,32]
  const float* E = (const float*)d_in[1];  // [1024,256]
  float* out = (float*)d_out;              // 8388608 + 2
  float* ws = (float*)d_ws;

  unsigned short* Ehi = (unsigned short*)ws;   // 262144 bf16 = 131072 floats
  unsigned short* Elo = Ehi + 262144;          // another 131072 floats
  float* enorm = ws + 262144;                  // [1024]
  float* counts = ws + 263168;                 // [1024]
  float* lossa = ws + 264192;                  // [1]
  float* pval = ws + 264256;                   // [8*32768]
  int* pidx = (int*)(ws + 264256 + 262144);    // [8*32768]

  hipMemsetAsync(counts, 0, 1088 * sizeof(float), stream);  // counts + lossa
  vq_prep<<<128, 256, 0, stream>>>(E, Ehi, Elo, enorm);
  vq_gemm<<<2048, 256, 0, stream>>>(X, Ehi, Elo, enorm, pval, pidx);
  vq_epi<<<512, 256, 0, stream>>>(X, E, pval, pidx, out, counts, lossa);
  vq_finalize<<<1, 256, 0, stream>>>(counts, lossa, out + 8388608);
}

// Round 3
// 164.894 us; speedup vs baseline: 2.1349x; 1.0910x over previous
//
#include <hip/hip_runtime.h>
#include <math.h>

typedef __attribute__((ext_vector_type(8))) short short8;
typedef __attribute__((ext_vector_type(4))) float float4v;

#define D_DIM 256
#define K_EMB 1024
#define HW_SZ 1024
#define N_TOT 32768
#define SMP_B (D_DIM * HW_SZ)  // per-batch stride in X (floats)

// ---- bf16 hi/lo split helpers (RNE) ----
__device__ __forceinline__ unsigned short f2bf(float x) {
  unsigned int u = __builtin_bit_cast(unsigned int, x);
  return (unsigned short)((u + 0x7fffu + ((u >> 16) & 1u)) >> 16);
}
__device__ __forceinline__ float bf2f(unsigned short h) {
  unsigned int u = ((unsigned int)h) << 16;
  return __builtin_bit_cast(float, u);
}

// ---- async global->LDS, 16B/lane (dest = wave-uniform base + lane*16) ----
typedef const __attribute__((address_space(1))) void GV;
typedef __attribute__((address_space(3))) void LV;
__device__ __forceinline__ void async16(const void* g, void* l) {
  __builtin_amdgcn_global_load_lds((GV*)g, (LV*)l, 16, 0, 0);
}

// ---------------------------------------------------------------- prep E ----
__global__ __launch_bounds__(256) void vq_prep_e(const float* __restrict__ E,
                                                 unsigned short* __restrict__ Ehi,
                                                 unsigned short* __restrict__ Elo,
                                                 float* __restrict__ enorm) {
  int tid = blockIdx.x * 256 + threadIdx.x;  // 32768 threads, 32 per code
  int c = tid >> 5;
  int d0 = (tid & 31) * 8;
  const float* p = E + c * D_DIM + d0;
  float s = 0.f;
  short8 hv, lv;
#pragma unroll
  for (int j = 0; j < 8; ++j) {
    float x = p[j];
    s = fmaf(x, x, s);
    unsigned short h = f2bf(x);
    hv[j] = (short)h;
    lv[j] = (short)f2bf(x - bf2f(h));
  }
  *(short8*)(Ehi + c * D_DIM + d0) = hv;
  *(short8*)(Elo + c * D_DIM + d0) = lv;
#pragma unroll
  for (int off = 1; off <= 16; off <<= 1) s += __shfl_xor(s, off);
  if ((tid & 31) == 0) enorm[c] = s;
}

// ---------------------------------------------------------------- prep X ----
// Transpose+convert X [b][d][hw] fp32 -> Xt_hi/Xt_lo [n=b*1024+hw][d] bf16.
// 64d x 64hw tile per block through LDS.
__global__ __launch_bounds__(256) void vq_prep_x(const float* __restrict__ X,
                                                 unsigned short* __restrict__ Xh,
                                                 unsigned short* __restrict__ Xl) {
  __shared__ float ts[64][65];  // +1 pad: 2-way-max banks on column reads
  const int t = threadIdx.x;
  const int bi = blockIdx.x;
  const int b = bi >> 6;
  const int dt = (bi >> 4) & 3;
  const int ht = bi & 15;
  const int d0 = dt * 64;
  const int hw0 = ht * 64;

  {
    const int dl = t >> 4;
    const int hl = (t & 15) * 4;
#pragma unroll
    for (int i = 0; i < 4; ++i) {
      float4 v = *(const float4*)(X + b * SMP_B + (d0 + dl + i * 16) * HW_SZ + hw0 + hl);
      ts[dl + i * 16][hl + 0] = v.x;
      ts[dl + i * 16][hl + 1] = v.y;
      ts[dl + i * 16][hl + 2] = v.z;
      ts[dl + i * 16][hl + 3] = v.w;
    }
  }
  __syncthreads();
#pragma unroll
  for (int p = 0; p < 2; ++p) {
    const int c = t + p * 256;
    const int dch = c & 7;   // d chunk of 8
    const int nl = c >> 3;   // 0..63
    short8 hv, lv;
#pragma unroll
    for (int j = 0; j < 8; ++j) {
      float x = ts[dch * 8 + j][nl];
      unsigned short h = f2bf(x);
      hv[j] = (short)h;
      lv[j] = (short)f2bf(x - bf2f(h));
    }
    const int n = b * 1024 + hw0 + nl;
    *(short8*)(Xh + n * D_DIM + d0 + dch * 8) = hv;
    *(short8*)(Xl + n * D_DIM + d0 + dch * 8) = lv;
  }
}

// ------------------------------------------------------------------ gemm ----
// Per block: 128 codes (M) x 128 samples (N), contraction D=256 in BK=32 chunks.
// All-bf16 frags (pre-split hi/lo), 3-term MFMA; d = enorm - 2S; per-sample
// argmin over the block's 128-code stripe -> partials [8 stripes][32768].
__global__ __launch_bounds__(256, 2) void vq_gemm(
    const unsigned short* __restrict__ Xh, const unsigned short* __restrict__ Xl,
    const unsigned short* __restrict__ Ehi, const unsigned short* __restrict__ Elo,
    const float* __restrict__ enorm, float* __restrict__ pval, int* __restrict__ pidx) {
  __shared__ unsigned short es_hi[128 * 32];  // 8 KB [code][d] d-contig
  __shared__ unsigned short es_lo[128 * 32];
  __shared__ unsigned short xs_hi[128 * 32];  // 8 KB [smp][d] d-contig
  __shared__ unsigned short xs_lo[128 * 32];
  __shared__ float rv[2][128];
  __shared__ int ri[2][128];

  const int t = threadIdx.x;
  const int i = blockIdx.x;
  // XCD-aware swizzle: all 8 code-stripes of one sample-block share i&7 -> same XCD
  const int cblk = (i >> 3) & 7;               // code stripe 0..7
  const int sblk = ((i >> 6) << 3) | (i & 7);  // sample block 0..255
  const int n0 = sblk * 128;

  const int lane = t & 63;
  const int wv = t >> 6;
  const int wm = wv >> 1;  // code half
  const int wn = wv & 1;   // sample half
  const int l15 = lane & 15;
  const int q = lane >> 4;

  float4v acc[4][4];
#pragma unroll
  for (int a = 0; a < 4; ++a)
#pragma unroll
    for (int c = 0; c < 4; ++c) acc[a][c] = {0.f, 0.f, 0.f, 0.f};

  const int srow = t >> 2;          // 0..63
  const int scol = (t & 3) * 8;     // 0,8,16,24
  const unsigned short* xhb = Xh + (n0 + srow) * D_DIM + scol;
  const unsigned short* xlb = Xl + (n0 + srow) * D_DIM + scol;
  const unsigned short* ehb = Ehi + (cblk * 128 + srow) * D_DIM + scol;
  const unsigned short* elb = Elo + (cblk * 128 + srow) * D_DIM + scol;
  char* xh_b = (char*)xs_hi;
  char* xl_b = (char*)xs_lo;
  char* eh_b = (char*)es_hi;
  char* el_b = (char*)es_lo;
  const int dst0 = t * 16;

  for (int dc = 0; dc < 8; ++dc) {
    const int d0 = dc * 32;
    async16(xhb + d0, xh_b + dst0);
    async16(xhb + 64 * D_DIM + d0, xh_b + dst0 + 4096);
    async16(xlb + d0, xl_b + dst0);
    async16(xlb + 64 * D_DIM + d0, xl_b + dst0 + 4096);
    async16(ehb + d0, eh_b + dst0);
    async16(ehb + 64 * D_DIM + d0, eh_b + dst0 + 4096);
    async16(elb + d0, el_b + dst0);
    async16(elb + 64 * D_DIM + d0, el_b + dst0 + 4096);
    __syncthreads();  // barrier drains vmcnt -> tiles visible

    short8 ah[4], al[4], xh[4], xl[4];
#pragma unroll
    for (int mi = 0; mi < 4; ++mi) {
      int row = wm * 64 + mi * 16 + l15;
      ah[mi] = *(const short8*)&es_hi[row * 32 + q * 8];
      al[mi] = *(const short8*)&es_lo[row * 32 + q * 8];
    }
#pragma unroll
    for (int ni = 0; ni < 4; ++ni) {
      int row = wn * 64 + ni * 16 + l15;
      xh[ni] = *(const short8*)&xs_hi[row * 32 + q * 8];
      xl[ni] = *(const short8*)&xs_lo[row * 32 + q * 8];
    }
#pragma unroll
    for (int mi = 0; mi < 4; ++mi)
#pragma unroll
      for (int ni = 0; ni < 4; ++ni)
        acc[mi][ni] = __builtin_amdgcn_mfma_f32_16x16x32_bf16(ah[mi], xh[ni], acc[mi][ni], 0, 0, 0);
#pragma unroll
    for (int mi = 0; mi < 4; ++mi)
#pragma unroll
      for (int ni = 0; ni < 4; ++ni)
        acc[mi][ni] = __builtin_amdgcn_mfma_f32_16x16x32_bf16(ah[mi], xl[ni], acc[mi][ni], 0, 0, 0);
#pragma unroll
    for (int mi = 0; mi < 4; ++mi)
#pragma unroll
      for (int ni = 0; ni < 4; ++ni)
        acc[mi][ni] = __builtin_amdgcn_mfma_f32_16x16x32_bf16(al[mi], xh[ni], acc[mi][ni], 0, 0, 0);
    __syncthreads();  // all frag reads done before next stage overwrites
  }

  // ---- per-sample argmin over this block's 128 codes ----
  float en[16];
#pragma unroll
  for (int mi = 0; mi < 4; ++mi)
#pragma unroll
    for (int r = 0; r < 4; ++r)
      en[mi * 4 + r] = enorm[cblk * 128 + wm * 64 + mi * 16 + q * 4 + r];

#pragma unroll
  for (int ni = 0; ni < 4; ++ni) {
    float bv = 1e30f;
    int bc = 0;
#pragma unroll
    for (int mi = 0; mi < 4; ++mi)
#pragma unroll
      for (int r = 0; r < 4; ++r) {
        float v = fmaf(-2.f, acc[mi][ni][r], en[mi * 4 + r]);
        if (v < bv) { bv = v; bc = wm * 64 + mi * 16 + q * 4 + r; }  // ascending c
      }
#pragma unroll
    for (int off = 16; off <= 32; off <<= 1) {  // merge the 4 q-groups
      float ov = __shfl_xor(bv, off);
      int oc = __shfl_xor(bc, off);
      if (ov < bv || (ov == bv && oc < bc)) { bv = ov; bc = oc; }
    }
    if (q == 0) {
      rv[wm][wn * 64 + ni * 16 + l15] = bv;
      ri[wm][wn * 64 + ni * 16 + l15] = cblk * 128 + bc;
    }
  }
  __syncthreads();
  if (t < 128) {  // merge code halves (wm0 codes < wm1 codes: tie keeps wm0)
    float v0 = rv[0][t];
    int c0 = ri[0][t];
    float v1 = rv[1][t];
    int c1 = ri[1][t];
    if (v1 < v0) { v0 = v1; c0 = c1; }
    pval[cblk * N_TOT + sblk * 128 + t] = v0;
    pidx[cblk * N_TOT + sblk * 128 + t] = c0;
  }
}

// -------------------------------------------------------------- epilogue ----
__global__ __launch_bounds__(256) void vq_epi(
    const float* __restrict__ X, const float* __restrict__ E,
    const float* __restrict__ pval, const int* __restrict__ pidx,
    float* __restrict__ out, float* __restrict__ counts,
    float* __restrict__ lossacc) {
  __shared__ int best_idx[64];
  __shared__ float es[64][257];  // gathered best-code rows, fp32
  __shared__ float loss_part[4];
  const int t = threadIdx.x;
  const int n0 = blockIdx.x * 64;
  const int b = n0 >> 10;
  const int hw0 = n0 & 1023;

  if (t < 64) {
    int n = n0 + t;
    float bv = 1e30f;
    int bc = 0;
#pragma unroll
    for (int s = 0; s < 8; ++s) {  // ascending stripe = ascending code range
      float v = pval[s * N_TOT + n];
      int c = pidx[s * N_TOT + n];
      if (v < bv || (v == bv && c < bc)) { bv = v; bc = c; }
    }
    best_idx[t] = bc;
    atomicAdd(&counts[bc], 1.0f);
  }
  __syncthreads();

  // gather the 64 best-code E rows into LDS (coalesced 1KB/wave global reads)
#pragma unroll
  for (int i = 0; i < 16; ++i) {
    const int c = t + i * 256;
    const int r = c >> 6;           // wave-uniform row
    const int col = (c & 63) * 4;
    float4 v = *(const float4*)(E + best_idx[r] * D_DIM + col);
    es[r][col + 0] = v.x;
    es[r][col + 1] = v.y;
    es[r][col + 2] = v.z;
    es[r][col + 3] = v.w;
  }
  __syncthreads();

  const int nl4 = (t & 15) * 4;
  const int drow = t >> 4;
  const float* Xp = X + b * SMP_B + hw0 + nl4;
  float* Op = out + b * SMP_B + hw0 + nl4;
  float lsum = 0.f;
#pragma unroll 4
  for (int d = drow; d < D_DIM; d += 16) {
    float4 x = *(const float4*)(Xp + d * HW_SZ);
    float4 qv;
    qv.x = es[nl4 + 0][d];
    qv.y = es[nl4 + 1][d];
    qv.z = es[nl4 + 2][d];
    qv.w = es[nl4 + 3][d];
    *(float4*)(Op + d * HW_SZ) = qv;
    float d0 = qv.x - x.x; lsum = fmaf(d0, d0, lsum);
    float d1 = qv.y - x.y; lsum = fmaf(d1, d1, lsum);
    float d2 = qv.z - x.z; lsum = fmaf(d2, d2, lsum);
    float d3 = qv.w - x.w; lsum = fmaf(d3, d3, lsum);
  }
#pragma unroll
  for (int off = 32; off >= 1; off >>= 1) lsum += __shfl_xor(lsum, off);
  if ((t & 63) == 0) loss_part[t >> 6] = lsum;
  __syncthreads();
  if (t == 0)
    atomicAdd(lossacc, loss_part[0] + loss_part[1] + loss_part[2] + loss_part[3]);
}

// -------------------------------------------------------------- finalize ----
__global__ __launch_bounds__(256) void vq_finalize(const float* __restrict__ counts,
                                                   const float* __restrict__ lossacc,
                                                   float* __restrict__ out_tail) {
  __shared__ float part[4];
  const int t = threadIdx.x;
  float s = 0.f;
#pragma unroll
  for (int k = t; k < K_EMB; k += 256) {
    float p = counts[k] * (1.0f / 32768.0f);
    s = fmaf(p, logf(p + 1e-10f), s);
  }
#pragma unroll
  for (int off = 32; off >= 1; off >>= 1) s += __shfl_xor(s, off);
  if ((t & 63) == 0) part[t >> 6] = s;
  __syncthreads();
  if (t == 0) {
    float tot = part[0] + part[1] + part[2] + part[3];
    out_tail[0] = 1.25f * lossacc[0] * (1.0f / 8388608.0f);
    out_tail[1] = expf(-tot);
  }
}

// ---------------------------------------------------------------- launch ----
extern "C" void kernel_launch(void* const* d_in, const int* in_sizes, int n_in,
                              void* d_out, int out_size, void* d_ws, size_t ws_size,
                              hipStream_t stream) {
  const float* X = (const float*)d_in[0];  // [32,256,32,32]
  const float* E = (const float*)d_in[1];  // [1024,256]
  float* out = (float*)d_out;              // 8388608 + 2
  float* ws = (float*)d_ws;

  // d_out doubles as scratch for transposed bf16 X (exactly 8388608 floats);
  // vq_epi fully overwrites it afterwards with the real output.
  unsigned short* Xh = (unsigned short*)out;      // [32768][256] bf16
  unsigned short* Xl = Xh + N_TOT * D_DIM;        // [32768][256] bf16

  unsigned short* Ehi = (unsigned short*)ws;  // 262144 bf16 = 131072 floats
  unsigned short* Elo = Ehi + 262144;
  float* enorm = ws + 262144;                 // [1024]
  float* counts = ws + 263168;                // [1024]
  float* lossa = ws + 264192;                 // [1]
  float* pval = ws + 264256;                  // [8*32768]
  int* pidx = (int*)(ws + 264256 + 262144);   // [8*32768]

  hipMemsetAsync(counts, 0, 1088 * sizeof(float), stream);  // counts + lossa
  vq_prep_e<<<128, 256, 0, stream>>>(E, Ehi, Elo, enorm);
  vq_prep_x<<<2048, 256, 0, stream>>>(X, Xh, Xl);
  vq_gemm<<<2048, 256, 0, stream>>>(Xh, Xl, Ehi, Elo, enorm, pval, pidx);
  vq_epi<<<512, 256, 0, stream>>>(X, E, pval, pidx, out, counts, lossa);
  vq_finalize<<<1, 256, 0, stream>>>(counts, lossa, out + 8388608);
}